// Round 12
// baseline (426.205 us; speedup 1.0000x reference)
//
#include <hip/hip_runtime.h>
#include <math.h>

typedef int intx4 __attribute__((ext_vector_type(4)));
typedef int intx8 __attribute__((ext_vector_type(8)));
typedef float floatx16 __attribute__((ext_vector_type(16)));

#define N_ROWS 8192
#define KDIM 1024
#define GEMM_BLOCKS (64 * 64)

// E8M0 scale bytes: 123 -> 2^-4 per side (data pre-scaled by 2^4 each side)
#define SCALE_WORD 0x7B7B7B7B

// order-preserving float->int encoding for atomicMax
__device__ __forceinline__ int fenc(float f) {
  int i = __float_as_int(f);
  return i >= 0 ? i : (i ^ 0x7fffffff);
}
__device__ __forceinline__ float fdec(int e) {
  int b = e >= 0 ? e : (e ^ 0x7fffffff);
  return __int_as_float(b);
}

// One WAVE per row (4 rows/block, no __syncthreads): computes 1/||x|| (fp32),
// writes row normalized*16 as e4m3 via HW cvt, inits the max slot.
// Also zeroes the gemm completion ticket (runs before gemm in stream order).
__global__ __launch_bounds__(256) void normalize_kernel(
    const float* __restrict__ ex, const float* __restrict__ ey,
    unsigned char* __restrict__ exn, unsigned char* __restrict__ eyn,
    int* __restrict__ rowmax, int* __restrict__ colmax,
    int* __restrict__ ticket) {
  if (blockIdx.x == 0 && threadIdx.x == 0) *ticket = 0;
  const int wave = threadIdx.x >> 6, lane = threadIdx.x & 63;
  const int gr = blockIdx.x * 4 + wave;  // 0..16383
  const float* x;
  unsigned char* out;
  int* mslot;
  int row;
  if (gr < N_ROWS) {
    x = ex; out = exn; mslot = rowmax; row = gr;
  } else {
    x = ey; out = eyn; mslot = colmax; row = gr - N_ROWS;
  }
  const float4* xr = (const float4*)(x + (size_t)row * KDIM);
  float4 v[4];
  float ss = 0.f;
#pragma unroll
  for (int j = 0; j < 4; ++j) {
    v[j] = xr[lane + j * 64];  // coalesced
    ss += v[j].x * v[j].x + v[j].y * v[j].y + v[j].z * v[j].z + v[j].w * v[j].w;
  }
#pragma unroll
  for (int off = 32; off > 0; off >>= 1) ss += __shfl_xor(ss, off, 64);
  const float rs = 16.0f * rsqrtf(fmaxf(ss, 1e-24f));  // 2^4 pre-scale
  int* op = (int*)(out + (size_t)row * KDIM);
#pragma unroll
  for (int j = 0; j < 4; ++j) {
    int w = __builtin_amdgcn_cvt_pk_fp8_f32(v[j].x * rs, v[j].y * rs, 0, false);
    w = __builtin_amdgcn_cvt_pk_fp8_f32(v[j].z * rs, v[j].w * rs, w, true);
    op[lane + j * 64] = w;
  }
  if (lane == 0) mslot[row] = (int)0x80000000;  // encoded -inf floor
}

// 128x128 tile GEMM (A @ B^T, row-major K-contiguous e4m3) using MX-scaled
// mfma_scale_f32_32x32x64_f8f6f4, fused with row/col max reduction AND the
// final entropy reduction (last-block-done pattern — kills the 3rd launch).
//
// Round-12 change: ONLY the fused finalize. gemm body is r11 verbatim
// (119.9 us, VGPR 64+64acc, 4 blocks/CU — at the combined VGPR+LDS
// occupancy limit; MFMA floor 29 us, LDS floor ~75 us, barrier slack the
// rest). Aux path was 81 us of the 201 total; this removes the finalize
// dispatch + its single-block serialization.
//
// Pipeline (verified r6/r8/r11): buffer_load->VGPR->ds_write; only vmcnt
// wait is the ds_write data dependence, placed AFTER compute:
//   LOAD(s+1); COMPUTE(buf s&1); WRITE(buf (s+1)&1); barrier
//
// LDS swizzle (verified r8+): 64-B rows, 16-B chunk c of row r at slot
// c ^ ((r>>1)&3) -> bank-group 4*(r&1) + slot covers all 8 groups x 2 lanes
// per quarter-wave. Fragment reads recover true chunk 2h+j, so operand bytes
// at (half,j,b) equal global k = k0+(2h+j)*16+b for BOTH A and B -> exact
// dot-product pairing (absmax 0.0 through r11).
__global__ __launch_bounds__(256, 4) void gemm_max_kernel(
    const unsigned char* __restrict__ A, const unsigned char* __restrict__ B,
    int* __restrict__ rowmax, int* __restrict__ colmax,
    int* __restrict__ ticket, float* __restrict__ out) {
  constexpr int TM = 128, BK = 64, K = KDIM;
  constexpr int BUF = TM * BK;                          // 8 KB per buffer
  __shared__ __align__(16) unsigned char sA[2 * BUF];   // 16 KB
  __shared__ __align__(16) unsigned char sB[2 * BUF];   // 16 KB

  const int bm = blockIdx.x, bn = blockIdx.y;
  const int tid = threadIdx.x;
  const int lane = tid & 63, wave = tid >> 6;
  const int wm = wave >> 1, wn = wave & 1;  // 2x2 waves of 64x64
  const int l32 = lane & 31, half = lane >> 5;
  const int fsw = (l32 >> 1) & 3;                 // f(row) = (row>>1)&3
  const int oLo = (((2 * half + 0) ^ fsw) << 4);  // swizzled slot offsets
  const int oHi = (((2 * half + 1) ^ fsw) << 4);

  const char* Ab = (const char*)(A + (size_t)bm * TM * K);
  const char* Bb = (const char*)(B + (size_t)bn * TM * K);

  floatx16 acc[2][2] = {};

  // Staging: wave w stages rows w*32..+31 of each tile per step.
  // Dest (linear lane*16): row r_d = wave*32 + (lane>>2), slot lane&3.
  // Source chunk = (lane&3) ^ f(r_d) = (lane&3) ^ ((lane>>3)&3); the +16-row
  // second write keeps the same offset (f(r+16)==f(r)).
  const int src_c16 = (((lane & 3) ^ ((lane >> 3) & 3)) << 4);
  const char* gA = Ab + (size_t)(wave * 32 + (lane >> 2)) * K + src_c16;
  const char* gB = Bb + (size_t)(wave * 32 + (lane >> 2)) * K + src_c16;
  unsigned char* wA = sA + wave * 2048 + lane * 16;  // linear dest (+buf,+it*1024)
  unsigned char* wB = sB + wave * 2048 + lane * 16;

  intx4 pf[4];  // prefetch regs: 2 A-chunks + 2 B-chunks (16 VGPRs)

#define LOADT(k0)                                            \
  do {                                                       \
    pf[0] = *(const intx4*)(gA + (size_t)(k0));              \
    pf[1] = *(const intx4*)(gA + (size_t)(k0) + 16 * K);     \
    pf[2] = *(const intx4*)(gB + (size_t)(k0));              \
    pf[3] = *(const intx4*)(gB + (size_t)(k0) + 16 * K);     \
  } while (0)

#define WRITET(buf)                                          \
  do {                                                       \
    *(intx4*)(wA + (buf)*BUF) = pf[0];                       \
    *(intx4*)(wA + (buf)*BUF + 1024) = pf[1];                \
    *(intx4*)(wB + (buf)*BUF) = pf[2];                       \
    *(intx4*)(wB + (buf)*BUF + 1024) = pf[3];                \
  } while (0)

#define COMPUTE(cur)                                                        \
  do {                                                                      \
    intx8 aF[2];                                                            \
    _Pragma("unroll") for (int mi = 0; mi < 2; ++mi) {                      \
      const unsigned char* aBase =                                          \
          &sA[(cur)*BUF + (wm * 64 + mi * 32 + l32) * BK];                  \
      const intx4 lo = *(const intx4*)(aBase + oLo);                        \
      const intx4 hi = *(const intx4*)(aBase + oHi);                        \
      aF[mi] = __builtin_shufflevector(lo, hi, 0, 1, 2, 3, 4, 5, 6, 7);     \
    }                                                                       \
    _Pragma("unroll") for (int ni = 0; ni < 2; ++ni) {                      \
      const unsigned char* bBase =                                          \
          &sB[(cur)*BUF + (wn * 64 + ni * 32 + l32) * BK];                  \
      const intx4 lo = *(const intx4*)(bBase + oLo);                        \
      const intx4 hi = *(const intx4*)(bBase + oHi);                        \
      const intx8 bF =                                                      \
          __builtin_shufflevector(lo, hi, 0, 1, 2, 3, 4, 5, 6, 7);          \
      _Pragma("unroll") for (int mi = 0; mi < 2; ++mi)                      \
          acc[mi][ni] = __builtin_amdgcn_mfma_scale_f32_32x32x64_f8f6f4(    \
              aF[mi], bF, acc[mi][ni], 0, 0, 0, SCALE_WORD, 0,              \
              SCALE_WORD);                                                  \
    }                                                                       \
  } while (0)

  LOADT(0);
  WRITET(0);
  __syncthreads();

  // unroll 1: keeps one pf set live (full unroll would hoist all -> spill)
#pragma unroll 1
  for (int step = 0; step < K / BK - 1; ++step) {
    LOADT((step + 1) * BK);   // in flight across the whole compute phase
    COMPUTE(step & 1);
    WRITET((step + 1) & 1);   // vmcnt wait is data-dependent, post-compute
    __syncthreads();
  }
  COMPUTE((K / BK - 1) & 1);

#undef LOADT
#undef WRITET
#undef COMPUTE

  // 32x32 C/D layout (m74/m101, dtype-independent):
  //   col = lane&31, row = (reg&3) + 8*(reg>>2) + 4*(lane>>5), reg in [0,16)
#pragma unroll
  for (int mi = 0; mi < 2; ++mi) {
#pragma unroll
    for (int reg = 0; reg < 16; ++reg) {
      float v = fmaxf(acc[mi][0][reg], acc[mi][1][reg]);
#pragma unroll
      for (int m = 1; m < 32; m <<= 1) v = fmaxf(v, __shfl_xor(v, m, 64));
      if (l32 == 0) {
        const int grow = bm * TM + wm * 64 + mi * 32 +
                         (reg & 3) + 8 * (reg >> 2) + 4 * half;
        atomicMax(&rowmax[grow], fenc(v));
      }
    }
  }
#pragma unroll
  for (int ni = 0; ni < 2; ++ni) {
    float v = -3.402823466e38f;
#pragma unroll
    for (int mi = 0; mi < 2; ++mi)
#pragma unroll
      for (int reg = 0; reg < 16; ++reg) v = fmaxf(v, acc[mi][ni][reg]);
    v = fmaxf(v, __shfl_xor(v, 32, 64));
    if (half == 0) {
      const int gcol = bn * TM + wn * 64 + ni * 32 + l32;
      atomicMax(&colmax[gcol], fenc(v));
    }
  }

  // ---- fused finalize: last block to finish reduces rowmax/colmax ----
  __shared__ int sdone;
  __shared__ float fr1[4], fr2[4];
  __threadfence();  // make this block's atomicMax results device-visible
  if (tid == 0) {
    const int t = atomicAdd(ticket, 1);
    sdone = (t == GEMM_BLOCKS - 1) ? 1 : 0;
  }
  __syncthreads();
  if (sdone) {
    float s1 = 0.f, s2 = 0.f;
    for (int i = tid; i < N_ROWS; i += 256) {
      s1 += 1.0f - fdec(rowmax[i]);
      s2 += 1.0f - fdec(colmax[i]);
    }
#pragma unroll
    for (int off = 32; off > 0; off >>= 1) {
      s1 += __shfl_down(s1, off, 64);
      s2 += __shfl_down(s2, off, 64);
    }
    if (lane == 0) {
      fr1[wave] = s1;
      fr2[wave] = s2;
    }
    __syncthreads();
    if (tid == 0) {
      const double SIGMA = 0.3;
      const double H_CONST =
          0.5 * log(2.0 * 3.14159265358979323846 * SIGMA * SIGMA) + 0.5;
      const float HS = (float)(H_CONST / SIGMA);
      out[0] = HS * (fr1[0] + fr1[1] + fr1[2] + fr1[3]);
      out[1] = HS * (fr2[0] + fr2[1] + fr2[2] + fr2[3]);
    }
  }
}

extern "C" void kernel_launch(void* const* d_in, const int* in_sizes, int n_in,
                              void* d_out, int out_size, void* d_ws, size_t ws_size,
                              hipStream_t stream) {
  const float* ex = (const float*)d_in[0];
  const float* ey = (const float*)d_in[1];
  float* out = (float*)d_out;
  char* ws = (char*)d_ws;

  unsigned char* exn = (unsigned char*)ws;                                   // 8 MB
  unsigned char* eyn = (unsigned char*)(ws + (size_t)N_ROWS * KDIM);         // 8 MB
  int* rowmax = (int*)(ws + (size_t)N_ROWS * KDIM * 2);                      // 32 KB
  int* colmax = rowmax + N_ROWS;                                             // 32 KB
  int* ticket = colmax + N_ROWS;                                             // 4 B

  normalize_kernel<<<2 * N_ROWS / 4, 256, 0, stream>>>(ex, ey, exn, eyn,
                                                       rowmax, colmax, ticket);
  gemm_max_kernel<<<dim3(64, 64), 256, 0, stream>>>(exn, eyn, rowmax, colmax,
                                                    ticket, out);
}

// Round 13
// 219.426 us; speedup vs baseline: 1.9424x; 1.9424x over previous
//
#include <hip/hip_runtime.h>
#include <math.h>

typedef int intx4 __attribute__((ext_vector_type(4)));
typedef int intx8 __attribute__((ext_vector_type(8)));
typedef float floatx16 __attribute__((ext_vector_type(16)));

#define N_ROWS 8192
#define KDIM 1024
#define GEMM_BLOCKS (64 * 64)

// E8M0 scale bytes: 123 -> 2^-4 per side (data pre-scaled by 2^4 each side)
#define SCALE_WORD 0x7B7B7B7B

// order-preserving float->int encoding for atomicMax
__device__ __forceinline__ int fenc(float f) {
  int i = __float_as_int(f);
  return i >= 0 ? i : (i ^ 0x7fffffff);
}
__device__ __forceinline__ float fdec(int e) {
  int b = e >= 0 ? e : (e ^ 0x7fffffff);
  return __int_as_float(b);
}

// One WAVE per row (4 rows/block, no __syncthreads): computes 1/||x|| (fp32),
// writes row normalized*16 as e4m3 via HW cvt, inits the max slot.
// Also zeroes the gemm completion ticket (runs before gemm in stream order).
__global__ __launch_bounds__(256) void normalize_kernel(
    const float* __restrict__ ex, const float* __restrict__ ey,
    unsigned char* __restrict__ exn, unsigned char* __restrict__ eyn,
    int* __restrict__ rowmax, int* __restrict__ colmax,
    int* __restrict__ ticket) {
  if (blockIdx.x == 0 && threadIdx.x == 0) *ticket = 0;
  const int wave = threadIdx.x >> 6, lane = threadIdx.x & 63;
  const int gr = blockIdx.x * 4 + wave;  // 0..16383
  const float* x;
  unsigned char* out;
  int* mslot;
  int row;
  if (gr < N_ROWS) {
    x = ex; out = exn; mslot = rowmax; row = gr;
  } else {
    x = ey; out = eyn; mslot = colmax; row = gr - N_ROWS;
  }
  const float4* xr = (const float4*)(x + (size_t)row * KDIM);
  float4 v[4];
  float ss = 0.f;
#pragma unroll
  for (int j = 0; j < 4; ++j) {
    v[j] = xr[lane + j * 64];  // coalesced
    ss += v[j].x * v[j].x + v[j].y * v[j].y + v[j].z * v[j].z + v[j].w * v[j].w;
  }
#pragma unroll
  for (int off = 32; off > 0; off >>= 1) ss += __shfl_xor(ss, off, 64);
  const float rs = 16.0f * rsqrtf(fmaxf(ss, 1e-24f));  // 2^4 pre-scale
  int* op = (int*)(out + (size_t)row * KDIM);
#pragma unroll
  for (int j = 0; j < 4; ++j) {
    int w = __builtin_amdgcn_cvt_pk_fp8_f32(v[j].x * rs, v[j].y * rs, 0, false);
    w = __builtin_amdgcn_cvt_pk_fp8_f32(v[j].z * rs, v[j].w * rs, w, true);
    op[lane + j * 64] = w;
  }
  if (lane == 0) mslot[row] = (int)0x80000000;  // encoded -inf floor
}

// 128x128 tile GEMM (A @ B^T, row-major K-contiguous e4m3) using MX-scaled
// mfma_scale_f32_32x32x64_f8f6f4, fused with row/col max reduction AND the
// final entropy reduction (last-block-done pattern).
//
// Round-13 change: r12's fused finalize WITHOUT __threadfence(). The fence
// compiled to L2 writeback/invalidate (per-XCD L2 non-coherent), and 4096
// staggered block-finishes continuously flushed the L2 that concurrent
// K-loops were streaming tiles from (gemm 120 -> 355 us, MfmaUtil 25 -> 8%,
// FETCH_SIZE unchanged: LLC absorbed it). Ordering without the fence:
//  - __syncthreads() forces s_waitcnt vmcnt(0) per wave (compiler-emitted
//    before s_barrier), so all this block's device-scope atomicMax ops have
//    COMPLETED at the coherent point before tid 0 bumps the ticket;
//  - the last block reads rowmax/colmax via agent-scope atomic loads
//    (bypass stale local caches), data-dependent on the ticket result.
// No cache-maintenance instructions emitted -> L2 stays warm.
//
// gemm body is r11 verbatim (119.9 us, VGPR 64+64acc, 4 blocks/CU).
// Pipeline (verified r6/r8/r11): LOAD(s+1); COMPUTE(s&1); WRITE((s+1)&1);
// barrier — only vmcnt wait is the ds_write data dependence, post-compute.
// LDS swizzle (verified r8+): chunk c of row r at slot c ^ ((r>>1)&3).
__global__ __launch_bounds__(256, 4) void gemm_max_kernel(
    const unsigned char* __restrict__ A, const unsigned char* __restrict__ B,
    int* __restrict__ rowmax, int* __restrict__ colmax,
    int* __restrict__ ticket, float* __restrict__ out) {
  constexpr int TM = 128, BK = 64, K = KDIM;
  constexpr int BUF = TM * BK;                          // 8 KB per buffer
  __shared__ __align__(16) unsigned char sA[2 * BUF];   // 16 KB
  __shared__ __align__(16) unsigned char sB[2 * BUF];   // 16 KB

  const int bm = blockIdx.x, bn = blockIdx.y;
  const int tid = threadIdx.x;
  const int lane = tid & 63, wave = tid >> 6;
  const int wm = wave >> 1, wn = wave & 1;  // 2x2 waves of 64x64
  const int l32 = lane & 31, half = lane >> 5;
  const int fsw = (l32 >> 1) & 3;                 // f(row) = (row>>1)&3
  const int oLo = (((2 * half + 0) ^ fsw) << 4);  // swizzled slot offsets
  const int oHi = (((2 * half + 1) ^ fsw) << 4);

  const char* Ab = (const char*)(A + (size_t)bm * TM * K);
  const char* Bb = (const char*)(B + (size_t)bn * TM * K);

  floatx16 acc[2][2] = {};

  // Staging: wave w stages rows w*32..+31 of each tile per step.
  // Dest (linear lane*16): row r_d = wave*32 + (lane>>2), slot lane&3.
  // Source chunk = (lane&3) ^ f(r_d) = (lane&3) ^ ((lane>>3)&3); the +16-row
  // second write keeps the same offset (f(r+16)==f(r)).
  const int src_c16 = (((lane & 3) ^ ((lane >> 3) & 3)) << 4);
  const char* gA = Ab + (size_t)(wave * 32 + (lane >> 2)) * K + src_c16;
  const char* gB = Bb + (size_t)(wave * 32 + (lane >> 2)) * K + src_c16;
  unsigned char* wA = sA + wave * 2048 + lane * 16;  // linear dest (+buf,+it*1024)
  unsigned char* wB = sB + wave * 2048 + lane * 16;

  intx4 pf[4];  // prefetch regs: 2 A-chunks + 2 B-chunks (16 VGPRs)

#define LOADT(k0)                                            \
  do {                                                       \
    pf[0] = *(const intx4*)(gA + (size_t)(k0));              \
    pf[1] = *(const intx4*)(gA + (size_t)(k0) + 16 * K);     \
    pf[2] = *(const intx4*)(gB + (size_t)(k0));              \
    pf[3] = *(const intx4*)(gB + (size_t)(k0) + 16 * K);     \
  } while (0)

#define WRITET(buf)                                          \
  do {                                                       \
    *(intx4*)(wA + (buf)*BUF) = pf[0];                       \
    *(intx4*)(wA + (buf)*BUF + 1024) = pf[1];                \
    *(intx4*)(wB + (buf)*BUF) = pf[2];                       \
    *(intx4*)(wB + (buf)*BUF + 1024) = pf[3];                \
  } while (0)

#define COMPUTE(cur)                                                        \
  do {                                                                      \
    intx8 aF[2];                                                            \
    _Pragma("unroll") for (int mi = 0; mi < 2; ++mi) {                      \
      const unsigned char* aBase =                                          \
          &sA[(cur)*BUF + (wm * 64 + mi * 32 + l32) * BK];                  \
      const intx4 lo = *(const intx4*)(aBase + oLo);                        \
      const intx4 hi = *(const intx4*)(aBase + oHi);                        \
      aF[mi] = __builtin_shufflevector(lo, hi, 0, 1, 2, 3, 4, 5, 6, 7);     \
    }                                                                       \
    _Pragma("unroll") for (int ni = 0; ni < 2; ++ni) {                      \
      const unsigned char* bBase =                                          \
          &sB[(cur)*BUF + (wn * 64 + ni * 32 + l32) * BK];                  \
      const intx4 lo = *(const intx4*)(bBase + oLo);                        \
      const intx4 hi = *(const intx4*)(bBase + oHi);                        \
      const intx8 bF =                                                      \
          __builtin_shufflevector(lo, hi, 0, 1, 2, 3, 4, 5, 6, 7);          \
      _Pragma("unroll") for (int mi = 0; mi < 2; ++mi)                      \
          acc[mi][ni] = __builtin_amdgcn_mfma_scale_f32_32x32x64_f8f6f4(    \
              aF[mi], bF, acc[mi][ni], 0, 0, 0, SCALE_WORD, 0,              \
              SCALE_WORD);                                                  \
    }                                                                       \
  } while (0)

  LOADT(0);
  WRITET(0);
  __syncthreads();

  // unroll 1: keeps one pf set live (full unroll would hoist all -> spill)
#pragma unroll 1
  for (int step = 0; step < K / BK - 1; ++step) {
    LOADT((step + 1) * BK);   // in flight across the whole compute phase
    COMPUTE(step & 1);
    WRITET((step + 1) & 1);   // vmcnt wait is data-dependent, post-compute
    __syncthreads();
  }
  COMPUTE((K / BK - 1) & 1);

#undef LOADT
#undef WRITET
#undef COMPUTE

  // 32x32 C/D layout (m74/m101, dtype-independent):
  //   col = lane&31, row = (reg&3) + 8*(reg>>2) + 4*(lane>>5), reg in [0,16)
#pragma unroll
  for (int mi = 0; mi < 2; ++mi) {
#pragma unroll
    for (int reg = 0; reg < 16; ++reg) {
      float v = fmaxf(acc[mi][0][reg], acc[mi][1][reg]);
#pragma unroll
      for (int m = 1; m < 32; m <<= 1) v = fmaxf(v, __shfl_xor(v, m, 64));
      if (l32 == 0) {
        const int grow = bm * TM + wm * 64 + mi * 32 +
                         (reg & 3) + 8 * (reg >> 2) + 4 * half;
        atomicMax(&rowmax[grow], fenc(v));
      }
    }
  }
#pragma unroll
  for (int ni = 0; ni < 2; ++ni) {
    float v = -3.402823466e38f;
#pragma unroll
    for (int mi = 0; mi < 2; ++mi)
#pragma unroll
      for (int reg = 0; reg < 16; ++reg) v = fmaxf(v, acc[mi][ni][reg]);
    v = fmaxf(v, __shfl_xor(v, 32, 64));
    if (half == 0) {
      const int gcol = bn * TM + wn * 64 + ni * 32 + l32;
      atomicMax(&colmax[gcol], fenc(v));
    }
  }

  // ---- fused finalize: last block to finish reduces rowmax/colmax ----
  // NO __threadfence() (see header). __syncthreads' implicit vmcnt(0) drain
  // guarantees this block's atomicMax ops completed at the coherent point
  // before the ticket increment.
  __shared__ int sdone;
  __shared__ float fr1[4], fr2[4];
  __syncthreads();
  if (tid == 0) {
    const int t = atomicAdd(ticket, 1);
    sdone = (t == GEMM_BLOCKS - 1) ? 1 : 0;
  }
  __syncthreads();
  if (sdone) {
    float s1 = 0.f, s2 = 0.f;
    for (int i = tid; i < N_ROWS; i += 256) {
      // agent-scope atomic loads: bypass possibly-stale local caches
      const int r = __hip_atomic_load(&rowmax[i], __ATOMIC_RELAXED,
                                      __HIP_MEMORY_SCOPE_AGENT);
      const int c = __hip_atomic_load(&colmax[i], __ATOMIC_RELAXED,
                                      __HIP_MEMORY_SCOPE_AGENT);
      s1 += 1.0f - fdec(r);
      s2 += 1.0f - fdec(c);
    }
#pragma unroll
    for (int off = 32; off > 0; off >>= 1) {
      s1 += __shfl_down(s1, off, 64);
      s2 += __shfl_down(s2, off, 64);
    }
    if (lane == 0) {
      fr1[wave] = s1;
      fr2[wave] = s2;
    }
    __syncthreads();
    if (tid == 0) {
      const double SIGMA = 0.3;
      const double H_CONST =
          0.5 * log(2.0 * 3.14159265358979323846 * SIGMA * SIGMA) + 0.5;
      const float HS = (float)(H_CONST / SIGMA);
      out[0] = HS * (fr1[0] + fr1[1] + fr1[2] + fr1[3]);
      out[1] = HS * (fr2[0] + fr2[1] + fr2[2] + fr2[3]);
    }
  }
}

extern "C" void kernel_launch(void* const* d_in, const int* in_sizes, int n_in,
                              void* d_out, int out_size, void* d_ws, size_t ws_size,
                              hipStream_t stream) {
  const float* ex = (const float*)d_in[0];
  const float* ey = (const float*)d_in[1];
  float* out = (float*)d_out;
  char* ws = (char*)d_ws;

  unsigned char* exn = (unsigned char*)ws;                                   // 8 MB
  unsigned char* eyn = (unsigned char*)(ws + (size_t)N_ROWS * KDIM);         // 8 MB
  int* rowmax = (int*)(ws + (size_t)N_ROWS * KDIM * 2);                      // 32 KB
  int* colmax = rowmax + N_ROWS;                                             // 32 KB
  int* ticket = colmax + N_ROWS;                                             // 4 B

  normalize_kernel<<<2 * N_ROWS / 4, 256, 0, stream>>>(ex, ey, exn, eyn,
                                                       rowmax, colmax, ticket);
  gemm_max_kernel<<<dim3(64, 64), 256, 0, stream>>>(exn, eyn, rowmax, colmax,
                                                    ticket, out);
}